// Round 8
// baseline (1227.312 us; speedup 1.0000x reference)
//
#include <hip/hip_runtime.h>

#define HH 56
#define WW 56
#define CC 512
#define BB 32
#define LL (HH*WW)
#define MM (BB*LL)     // 100352 tokens
#define HID 2048

typedef __attribute__((ext_vector_type(8))) __bf16 bf16x8;
typedef __attribute__((ext_vector_type(4))) float f32x4;
typedef __attribute__((ext_vector_type(4))) short s16x4;

__device__ __forceinline__ short f2bf(float f) {
    union { float f; unsigned u; } c; c.f = f;
    unsigned r = c.u + 0x7fffu + ((c.u >> 16) & 1u);   // round-to-nearest-even
    return (short)(r >> 16);
}
__device__ __forceinline__ float bf2f(short s) {
    union { unsigned u; float f; } c; c.u = ((unsigned)(unsigned short)s) << 16;
    return c.f;
}

// fast gelu: v * t/(t+1), t = e^{2*0.7978845608*(v+0.044715 v^3)}
__device__ __forceinline__ float gelu_fast(float v) {
    float xg = 0.7978845608f * (v + 0.044715f * v * v * v);
    xg = fminf(xg, 15.0f);
    float t = __expf(2.0f * xg);
    return v * (t / (t + 1.0f));
}

// ---------------- f32 -> bf16 weight conversion ----------------
__global__ __launch_bounds__(256) void cvt_bf16(const float* __restrict__ in,
                                                short* __restrict__ out, int n) {
    int i = blockIdx.x * 256 + threadIdx.x;
    if (i < n) out[i] = f2bf(in[i]);
}

// ---------------- LayerNorm over 512 channels, 1 row / block ----------------
__global__ __launch_bounds__(256) void ln512(const float* __restrict__ x,
                                             const float* __restrict__ g,
                                             const float* __restrict__ b,
                                             short* __restrict__ out) {
    const int row = blockIdx.x;
    const int t = threadIdx.x;
    const float2 v = ((const float2*)(x + (long)row * 512))[t];
    float s = v.x + v.y;
    float q = v.x * v.x + v.y * v.y;
#pragma unroll
    for (int off = 32; off > 0; off >>= 1) {
        s += __shfl_xor(s, off, 64);
        q += __shfl_xor(q, off, 64);
    }
    __shared__ float red[8];
    const int wv = t >> 6;
    if ((t & 63) == 0) { red[wv] = s; red[4 + wv] = q; }
    __syncthreads();
    s = red[0] + red[1] + red[2] + red[3];
    q = red[4] + red[5] + red[6] + red[7];
    const float mu = s * (1.0f / 512.0f);
    const float rs = rsqrtf(q * (1.0f / 512.0f) - mu * mu + 1e-5f);
    const float2 gv = ((const float2*)g)[t];
    const float2 bv = ((const float2*)b)[t];
    const float y0 = (v.x - mu) * rs * gv.x + bv.x;
    const float y1 = (v.y - mu) * rs * gv.y + bv.y;
    union { short s2[2]; unsigned u; } o;
    o.s2[0] = f2bf(y0); o.s2[1] = f2bf(y1);
    ((unsigned*)out)[(long)row * 256 + t] = o.u;
}

// ---------------- spatial (window) MLP + residual ----------------
__global__ __launch_bounds__(256) void spatial_mlp(const short* __restrict__ xn,
                                                   const float* __restrict__ x,
                                                   const float* __restrict__ sw,
                                                   const float* __restrict__ sb,
                                                   float* x1) {
    const int head = blockIdx.y;
    const int t = threadIdx.x;
    const int ch = t & 31;
    const int wloc = t >> 5;
    const int win = blockIdx.x * 8 + wloc;        // 0..2591
    const int b = win / 81;
    const int rr = win - b * 81;
    const int wi = rr / 9;
    const int wj = rr - wi * 9;
    const int c = head * 32 + ch;

    float xv[49];
#pragma unroll
    for (int j = 0; j < 49; j++) {
        const int pr = wi * 7 + j / 7 - 4;        // padded row - P_T
        const int pc = wj * 7 + j % 7 - 4;        // padded col - P_L
        float v = 0.0f;
        if (pr >= 0 && pr < 56 && pc >= 0 && pc < 56)
            v = bf2f(xn[((long)((b * 56 + pr) * 56 + pc)) * 512 + c]);
        xv[j] = v;
    }

    const float* swh = sw + head * 2401;
    const float* sbh = sb + head * 49;

#pragma unroll 1
    for (int t7 = 0; t7 < 7; t7++) {
        float acc[7];
#pragma unroll
        for (int ii = 0; ii < 7; ii++) acc[ii] = sbh[t7 * 7 + ii];
#pragma unroll
        for (int ii = 0; ii < 7; ii++) {
            const float* swr = swh + (t7 * 7 + ii) * 49;
#pragma unroll
            for (int j = 0; j < 49; j++)
                acc[ii] = fmaf(swr[j], xv[j], acc[ii]);
        }
        const int pr = wi * 7 + t7 - 4;
        if (pr >= 0 && pr < 56) {
#pragma unroll
            for (int ii = 0; ii < 7; ii++) {
                const int pc = wj * 7 + ii - 4;
                if (pc >= 0 && pc < 56) {
                    const long idx = ((long)((b * 56 + pr) * 56 + pc)) * 512 + c;
                    x1[idx] = x[idx] + acc[ii];
                }
            }
        }
    }
}

// ------- 256x128 4-wave bf16 GEMM, per-wave 128x64, ring-3, 2 blocks/CU ------
// A[M,K] row-major, Bw[N,K] row-major (B^T). BK=32.
// r5's proven schedule (best per-tile so far), with 2x FLOPs per LDS byte:
//   per K-tile: stage(t+2) [6 gload_lds]; 12x ds_read_b128; lgkmcnt(0);
//   setprio(1); 32 MFMA; setprio(0); counted vmcnt(6); ONE s_barrier.
// Ring-3 x (A 16KB + B 8KB) = 72 KB -> 2 blocks/CU co-resident (the r6/r7
// failure was 1 block/CU: barrier stalls were dead time).
// T2 XOR swizzle (key=row&3 on 64B rows): uniform 8 touches/bank = 0 conflicts.
// MFMA operand-swapped -> vectorized 16B/8B epilogue stores. T1 XCD remap.
template <int K, int N, bool GELU>
__global__ __launch_bounds__(256, 2) void gemm2x(const short* __restrict__ A,
                                                 const short* __restrict__ Bw,
                                                 const float* __restrict__ bias,
                                                 const float* res,
                                                 void* Cout) {
    __shared__ __attribute__((aligned(16))) short S[36864];  // 72 KB
    const int tid = threadIdx.x;
    const int lane = tid & 63;
    const int wid = tid >> 6;          // 0..3
    const int wr = wid >> 1;           // 0..1  M-half (128 rows)
    const int wc = wid & 1;            // 0..1  N-half (64 cols)
    const int lr = lane & 15;
    const int kg = (lane >> 4) & 3;

    // T1: bijective XCD-aware remap (nwg % 8 == 0)
    const int gx = gridDim.x;
    const int lin = blockIdx.y * gx + blockIdx.x;
    const int cpx = (gx * gridDim.y) >> 3;
    const int orig = (lin & 7) * cpx + (lin >> 3);
    const long mBase = (long)(orig / gx) * 256;
    const long nBase = (long)(orig % gx) * 128;

    // staging source (pre-swizzled column chunk; LDS dest linear)
    const int sRow = tid >> 2;                        // 0..63
    const int sChunk = (tid & 3) ^ ((tid >> 2) & 3);  // key = row&3
    const short* aS = A + (mBase + sRow) * K + sChunk * 8;
    const short* bS = Bw + (nBase + sRow) * K + sChunk * 8;

    // ring slot r: A at r*16384, B at 49152 + r*8192
    auto stage = [&](int rbuf, int t) {
        const long k0 = (long)t * 32;
        char* Ad = (char*)S + rbuf * 16384 + tid * 16;
        char* Bd = (char*)S + 49152 + rbuf * 8192 + tid * 16;
#pragma unroll
        for (int j = 0; j < 4; ++j)       // A: 256 rows x 32 k
            __builtin_amdgcn_global_load_lds(
                (const __attribute__((address_space(1))) void*)(aS + k0 + (long)j * 64 * K),
                (__attribute__((address_space(3))) void*)(Ad + j * 4096), 16, 0, 0);
#pragma unroll
        for (int j = 0; j < 2; ++j)       // B: 128 rows x 32 k
            __builtin_amdgcn_global_load_lds(
                (const __attribute__((address_space(1))) void*)(bS + k0 + (long)j * 64 * K),
                (__attribute__((address_space(3))) void*)(Bd + j * 4096), 16, 0, 0);
    };

    // fragment LDS byte offsets: row*64 + (kg^(row&3))*16, row&3 == lr&3
    const int swz = (kg ^ (lr & 3)) * 16;
    const int aOff = (wr * 128 + lr) * 64 + swz;      // + m*1024, m=0..7
    const int bOff = (wc * 64 + lr) * 64 + swz;       // + n*1024, n=0..3

    f32x4 acc[8][4] = {};

    stage(0, 0); stage(1, 1);                         // 12 loads in flight
    asm volatile("s_waitcnt vmcnt(6)" ::: "memory");  // tile 0 landed
    __builtin_amdgcn_s_barrier();

    const int NT = K / 32;
    int cb = 0;
    for (int t = 0; t < NT; ++t) {
        if (t + 2 < NT) {
            const int sb = cb >= 1 ? cb - 1 : 2;      // (cb+2)%3
            stage(sb, t + 2);
        }
        const char* Ab = (const char*)S + cb * 16384;
        const char* Bb = (const char*)S + 49152 + cb * 8192;
        bf16x8 af[8], bfv[4];
#pragma unroll
        for (int m = 0; m < 8; ++m) af[m] = *(const bf16x8*)(Ab + aOff + m * 1024);
#pragma unroll
        for (int n = 0; n < 4; ++n) bfv[n] = *(const bf16x8*)(Bb + bOff + n * 1024);
        asm volatile("s_waitcnt lgkmcnt(0)" ::: "memory");
        __builtin_amdgcn_s_setprio(1);
#pragma unroll
        for (int m = 0; m < 8; ++m)
#pragma unroll
            for (int n = 0; n < 4; ++n)
                acc[m][n] = __builtin_amdgcn_mfma_f32_16x16x32_bf16(bfv[n], af[m],
                                                                    acc[m][n], 0, 0, 0);
        __builtin_amdgcn_s_setprio(0);
        // boundary: tile t+1's 6 loads landed (t+2's 6 stay in flight)
        if (t + 2 < NT)      asm volatile("s_waitcnt vmcnt(6)" ::: "memory");
        else if (t + 1 < NT) asm volatile("s_waitcnt vmcnt(0)" ::: "memory");
        __builtin_amdgcn_s_barrier();
        cb = cb + 1 == 3 ? 0 : cb + 1;
    }

    // epilogue: operand-swapped fragment = C^T layout:
    //   C row  = mBase + wr*128 + m*16 + lr
    //   C cols = nBase + wc*64 + n*16 + kg*4 + (0..3)   (consecutive)
#pragma unroll
    for (int n = 0; n < 4; ++n) {
        const long col0 = nBase + wc * 64 + n * 16 + kg * 4;
        const f32x4 bv4 = *(const f32x4*)(bias + col0);
#pragma unroll
        for (int m = 0; m < 8; ++m) {
            const long row = mBase + wr * 128 + m * 16 + lr;
            const long idx = row * N + col0;
            if (GELU) {
                s16x4 o;
#pragma unroll
                for (int r = 0; r < 4; ++r)
                    o[r] = f2bf(gelu_fast(acc[m][n][r] + bv4[r]));
                *(s16x4*)((short*)Cout + idx) = o;
            } else {
                const f32x4 rv = *(const f32x4*)(res + idx);
                f32x4 o;
#pragma unroll
                for (int r = 0; r < 4; ++r) o[r] = acc[m][n][r] + bv4[r] + rv[r];
                *(f32x4*)((float*)Cout + idx) = o;
            }
        }
    }
}

extern "C" void kernel_launch(void* const* d_in, const int* in_sizes, int n_in,
                              void* d_out, int out_size, void* d_ws, size_t ws_size,
                              hipStream_t stream) {
    const float* x    = (const float*)d_in[0];
    const float* n1g  = (const float*)d_in[1];
    const float* n1b  = (const float*)d_in[2];
    const float* sw   = (const float*)d_in[3];
    const float* sb   = (const float*)d_in[4];
    const float* n2g  = (const float*)d_in[5];
    const float* n2b  = (const float*)d_in[6];
    const float* fc1w = (const float*)d_in[7];
    const float* fc1b = (const float*)d_in[8];
    const float* fc2w = (const float*)d_in[9];
    const float* fc2b = (const float*)d_in[10];
    float* out = (float*)d_out;

    // workspace layout (bytes)
    char* ws = (char*)d_ws;
    short* xn  = (short*)ws;                      // MM*512*2    = 102,760,448  (xn, then xn2)
    short* hb  = (short*)(ws + 102760448);        // MM*2048*2   = 411,041,792
    short* w1b = (short*)(ws + 513802240);        // 2048*512*2  =   2,097,152
    short* w2b = (short*)(ws + 515899392);        // 512*2048*2  =   2,097,152

    cvt_bf16<<<4096, 256, 0, stream>>>(fc1w, w1b, 2048 * 512);
    cvt_bf16<<<4096, 256, 0, stream>>>(fc2w, w2b, 512 * 2048);

    // LN1: x -> xn (bf16)
    ln512<<<MM, 256, 0, stream>>>(x, n1g, n1b, xn);

    // spatial MLP + residual: x1 = x + y  (into d_out)
    spatial_mlp<<<dim3(324, 16), 256, 0, stream>>>(xn, x, sw, sb, out);

    // LN2: x1 -> xn2 (bf16, reuse xn buffer)
    ln512<<<MM, 256, 0, stream>>>(out, n2g, n2b, xn);

    // FC1 + gelu -> h (bf16)   grid: 16 N-tiles x 392 M-tiles
    gemm2x<512, 2048, true><<<dim3(16, 392), 256, 0, stream>>>(xn, w1b, fc1b, nullptr, hb);

    // FC2 + bias + residual -> out (f32, reads x1 from d_out in place)
    gemm2x<2048, 512, false><<<dim3(4, 392), 256, 0, stream>>>(hb, w2b, fc2b, out, out);
}